// Round 12
// baseline (350.547 us; speedup 1.0000x reference)
//
#include <hip/hip_runtime.h>
#include <hip/hip_fp16.h>

#define NN 50000
#define NE 800000
#define NBK 196        // ceil(NN/256) node-range buckets
#define BCAP 8192      // per-bucket edge capacity (mean ~4350)
#define GEMM_GRID 391  // 782 row-tiles, 2 per block
#define WTOT 49152     // W1 16384 + W2 8192 + W3 8192 + W4 16384

typedef unsigned int uint;
typedef unsigned short ushort;
typedef __attribute__((ext_vector_type(8))) short short8v;
typedef __attribute__((ext_vector_type(4))) float float4v;

static __device__ __forceinline__ float waveReduceSum(float v) {
#pragma unroll
  for (int o = 32; o > 0; o >>= 1) v += __shfl_xor(v, o);
  return v;
}
static __device__ __forceinline__ float waveReduceMax(float v) {
#pragma unroll
  for (int o = 32; o > 0; o >>= 1) v = fmaxf(v, __shfl_xor(v, o));
  return v;
}
static __device__ __forceinline__ uint f2bf(float f) {
  uint u = __float_as_uint(f);
  return (u + 0x7fffu + ((u >> 16) & 1u)) >> 16;  // RNE; inputs finite
}
// fp16 pair unpack (H storage)
static __device__ __forceinline__ float h_lo(uint u) {
  __half2 h = *(const __half2*)&u;
  return __half2float(h.x);
}
static __device__ __forceinline__ float h_hi(uint u) {
  __half2 h = *(const __half2*)&u;
  return __half2float(h.y);
}
static __device__ __forceinline__ int waveInclScan(int v, int lane) {
#pragma unroll
  for (int o = 1; o < 64; o <<= 1) {
    int u = __shfl_up(v, o);
    if (lane >= o) v += u;
  }
  return v;
}
// split fp32 -> bf16 hi + bf16 lo (x ~= hi + lo, residual ~2^-16 relative)
static __device__ __forceinline__ void split8(const float* f, short8v& hi, short8v& lo) {
#pragma unroll
  for (int j = 0; j < 8; ++j) {
    uint h = f2bf(f[j]);
    hi[j] = (short)h;
    float hf = __uint_as_float(h << 16);
    lo[j] = (short)f2bf(f[j] - hf);
  }
}

// ---------------- bucketed CSR build ----------------
__global__ __launch_bounds__(256) void k_bucket(
    const int* __restrict__ esrc, const int* __restrict__ edst,
    uint* __restrict__ ebuf, int* __restrict__ bcnt) {
  __shared__ int hist[NBK];
  __shared__ int gbase[NBK];
  int tid = threadIdx.x;
  for (int i = tid; i < NBK; i += 256) hist[i] = 0;
  __syncthreads();
  const int ET = NE + NN;
  int base = blockIdx.x * 4096;
  int myb[16];
  uint mypk[16];
#pragma unroll
  for (int j = 0; j < 16; ++j) {
    int e = base + j * 256 + tid;  // coalesced per j
    int s, d;
    if (e < NE) { s = esrc[e]; d = edst[e]; }
    else if (e < ET) { s = e - NE; d = s; }   // self loop
    else { myb[j] = -1; continue; }
    int b = d >> 8;
    myb[j] = b;
    mypk[j] = (uint)s | ((uint)(d & 255) << 16);
    atomicAdd(&hist[b], 1);
  }
  __syncthreads();
  for (int i = tid; i < NBK; i += 256) {
    int h = hist[i];
    gbase[i] = h > 0 ? atomicAdd(&bcnt[i], h) : 0;
    hist[i] = 0;  // reuse as cursor
  }
  __syncthreads();
#pragma unroll
  for (int j = 0; j < 16; ++j) {
    int b = myb[j];
    if (b < 0) continue;
    int r = atomicAdd(&hist[b], 1);
    int pos = gbase[b] + r;
    if (pos < BCAP) ebuf[(size_t)b * BCAP + pos] = mypk[j];
  }
}
__global__ __launch_bounds__(256) void k_csr(
    const uint* __restrict__ ebuf, const int* __restrict__ bcnt,
    int* __restrict__ indptr, int* __restrict__ srcs) {
  __shared__ int h[256];
  __shared__ int cur[256];
  __shared__ int wsm[4];
  __shared__ int bbs;
  int tid = threadIdx.x, b = blockIdx.x;
  int lane = tid & 63, wv = tid >> 6;
  int v = (tid < NBK) ? bcnt[tid] : 0;
  int inc = waveInclScan(v, lane);
  if (lane == 63) wsm[wv] = inc;
  __syncthreads();
  int woff = 0;
  for (int k = 0; k < wv; ++k) woff += wsm[k];
  if (tid == b) bbs = inc - v + woff;
  h[tid] = 0;
  __syncthreads();
  int bbase = bbs;
  int cnt = bcnt[b];
  const uint* eb = ebuf + (size_t)b * BCAP;
  for (int i = tid; i < cnt; i += 256) atomicAdd(&h[eb[i] >> 16], 1);
  __syncthreads();
  int hv = h[tid];
  int inc2 = waveInclScan(hv, lane);
  if (lane == 63) wsm[wv] = inc2;
  __syncthreads();
  int woff2 = 0;
  for (int k = 0; k < wv; ++k) woff2 += wsm[k];
  int nodeExcl = inc2 - hv + woff2;
  int node = b * 256 + tid;
  if (node < NN) indptr[node] = bbase + nodeExcl;
  if (node == NN - 1) indptr[NN] = bbase + nodeExcl + hv;
  cur[tid] = nodeExcl;
  __syncthreads();
  for (int i = tid; i < cnt; i += 256) {
    uint pk = eb[i];
    int r = atomicAdd(&cur[pk >> 16], 1);
    srcs[bbase + r] = (int)(pk & 0xffffu);
  }
}

// ---------------- W pre-permute (+ bcnt zero) ----------------
__global__ void k_wprep(const float* __restrict__ W1, const float* __restrict__ W2,
                        const float* __restrict__ W3, const float* __restrict__ W4,
                        ushort* __restrict__ hi, ushort* __restrict__ lo,
                        int* __restrict__ bcnt) {
  int i = blockIdx.x * 256 + threadIdx.x;
  if (i < NBK) bcnt[i] = 0;  // block 0 zeroes bucket counters
  if (i >= WTOT) return;
  const float* W; int DO, base;
  if (i < 16384)      { W = W1; DO = 128; base = 0; }
  else if (i < 24576) { W = W2; DO = 64;  base = 16384; }
  else if (i < 32768) { W = W3; DO = 128; base = 24576; }
  else                { W = W4; DO = 128; base = 32768; }
  int idx = i - base;
  int k = idx / DO, col = idx % DO;
  float w = W[idx];
  uint h = f2bf(w);
  float hf = __uint_as_float(h << 16);
  uint l2 = f2bf(w - hf);
  int CT = DO >> 4;
  int fo = base + (((k >> 5) * CT + (col >> 4)) * 64 + ((col & 15) | (((k >> 3) & 3) << 4))) * 8 + (k & 7);
  hi[fo] = (ushort)h;
  lo[fo] = (ushort)l2;
}

// ---------------- MFMA GEMM (split-bf16, fp32-grade) + logit dots ----------
template <int K, int DO, bool NORM>
__global__ __launch_bounds__(256) void k_gemm_mfma(
    const float* __restrict__ X, const ushort* __restrict__ Whi,
    const ushort* __restrict__ Wlo,
    const float* __restrict__ avs, const float* __restrict__ avd,
    ushort* __restrict__ H, float* __restrict__ als, float* __restrict__ ald, int n) {
  constexpr int KS = K / 32, CT = DO / 16;
  constexpr int W4N = K * DO / 8;  // uint4 words per array
  __shared__ ushort sWhi[K * DO];
  __shared__ ushort sWlo[K * DO];
  __shared__ float sas[DO], sad[DO];
  int tid = threadIdx.x;
  for (int i = tid; i < DO; i += 256) { sas[i] = avs[i]; sad[i] = avd[i]; }
  {
    const uint4* ghi = (const uint4*)Whi;
    const uint4* glo = (const uint4*)Wlo;
    uint4* shi = (uint4*)sWhi;
    uint4* slo = (uint4*)sWlo;
    for (int i = tid; i < W4N; i += 256) { shi[i] = ghi[i]; slo[i] = glo[i]; }
  }
  __syncthreads();
  int lane = tid & 63, wv = tid >> 6;
  int ntiles = (n + 63) >> 6;
  for (int tile = blockIdx.x; tile < ntiles; tile += gridDim.x) {
    int r0 = tile * 64 + wv * 16;
    if (r0 >= n) continue;
    int row = r0 + (lane & 15);
    int sub = lane >> 4;
    const float* xrow = X + (size_t)row * K;
    float xr[KS][8];
#pragma unroll
    for (int s = 0; s < KS; ++s) {
      *(float4*)&xr[s][0] = *(const float4*)(xrow + s * 32 + sub * 8);
      *(float4*)&xr[s][4] = *(const float4*)(xrow + s * 32 + sub * 8 + 4);
    }
    if (NORM) {
      float ss = 0.f;
#pragma unroll
      for (int s = 0; s < KS; ++s)
#pragma unroll
        for (int j = 0; j < 8; ++j) ss += xr[s][j] * xr[s][j];
      ss += __shfl_xor(ss, 16);
      ss += __shfl_xor(ss, 32);
      float sc = 1.0f / fmaxf(sqrtf(ss), 1e-12f);
#pragma unroll
      for (int s = 0; s < KS; ++s)
#pragma unroll
        for (int j = 0; j < 8; ++j) xr[s][j] *= sc;
    }
    float4v acc[CT];
#pragma unroll
    for (int c = 0; c < CT; ++c) acc[c] = (float4v){0.f, 0.f, 0.f, 0.f};
#pragma unroll
    for (int s = 0; s < KS; ++s) {
      short8v ahi, alo;
      split8(xr[s], ahi, alo);
#pragma unroll
      for (int c = 0; c < CT; ++c) {
        short8v bhi = *(const short8v*)&sWhi[(s * CT + c) * 512 + lane * 8];
        short8v blo = *(const short8v*)&sWlo[(s * CT + c) * 512 + lane * 8];
        acc[c] = __builtin_amdgcn_mfma_f32_16x16x32_bf16(ahi, bhi, acc[c], 0, 0, 0);
        acc[c] = __builtin_amdgcn_mfma_f32_16x16x32_bf16(ahi, blo, acc[c], 0, 0, 0);
        acc[c] = __builtin_amdgcn_mfma_f32_16x16x32_bf16(alo, bhi, acc[c], 0, 0, 0);
      }
    }
    int rbase = r0 + (sub << 2);
    float alsp[4] = {0.f, 0.f, 0.f, 0.f};
    float aldp[4] = {0.f, 0.f, 0.f, 0.f};
#pragma unroll
    for (int c = 0; c < CT; ++c) {
      int col = (c << 4) + (lane & 15);
      float as_ = sas[col], ad_ = sad[col];
#pragma unroll
      for (int j = 0; j < 4; ++j) {
        float v = acc[c][j];
        alsp[j] += v * as_;
        aldp[j] += v * ad_;
        uint bv = (uint)__half_as_ushort(__float2half(v));
        uint nb = __shfl_xor(bv, 1);
        if (!(lane & 1)) {
          *(uint*)&H[(size_t)(rbase + j) * DO + col] = bv | (nb << 16);
        }
      }
    }
#pragma unroll
    for (int j = 0; j < 4; ++j) {
      float vs = alsp[j], vd = aldp[j];
#pragma unroll
      for (int o = 1; o < 16; o <<= 1) { vs += __shfl_xor(vs, o); vd += __shfl_xor(vd, o); }
      if ((lane & 15) == 0) { als[rbase + j] = vs; ald[rbase + j] = vd; }
    }
  }
}

// ---------------- fused softmax + aggregation: 2 waves per node ------------
// Block = 4 waves = 2 nodes. Each wave owns a contiguous half of its node's
// edge list (~deg/2 edges) -> ONE masked ILP gather block per wave (depth 8).
// Cross-wave max/sum/partial combine via LDS + 3 syncthreads (uniform path).
// MODE 0: +bias ; MODE 1: +bias,relu ; MODE 2 (D=64): +bias, l2norm, fused q
template <int D, int MODE>
__global__ __launch_bounds__(256) void k_attn_aggr(
    const int* __restrict__ indptr, const int* __restrict__ srcs,
    const float* __restrict__ als, const float* __restrict__ ald,
    const ushort* __restrict__ H, const float* __restrict__ bias,
    float* __restrict__ out, const float* __restrict__ cluster,
    float* __restrict__ qout, int n) {
  constexpr int CAP = 256;
  constexpr int HSTR = D / 4;  // uint2 per H row
  __shared__ float slg[2][CAP];
  __shared__ uint soff[2][CAP];
  __shared__ float wredm[4], wreds[4];
  __shared__ float pacc[2][64][5];  // stride 5: conflict-free lane access
  __shared__ float scl[MODE == 2 ? 16 : 1][MODE == 2 ? 68 : 1];
  __shared__ float sz[2][MODE == 2 ? 64 : 1];
  int tid = threadIdx.x;
  int l = tid & 63;
  int wv = tid >> 6;
  int nd = wv >> 1, q = wv & 1;
  if (MODE == 2) {
    for (int i = tid; i < 1024; i += 256) scl[i >> 6][i & 63] = cluster[i];
  }
  int w = blockIdx.x * 2 + nd;
  bool act = (w < n);
  int s0 = 0, deg = 0;
  float ad = 0.f;
  if (act) { s0 = indptr[w]; deg = indptr[w + 1] - s0; ad = ald[w]; }
  bool staged = act && (deg <= CAP);
  int h1 = (deg + 1) >> 1;
  int myS = q ? h1 : 0;
  int myE = q ? deg : h1;
  const uint2* Hr = (const uint2*)H;
  // ---- sweep 1: logits (+ stage src row-offsets), per-wave max ----
  float mx = -1e30f;
  for (int t = myS + l; t < myE; t += 64) {
    int s = srcs[s0 + t];
    float v = als[s] + ad;
    v = v >= 0.f ? v : 0.2f * v;
    if (staged) { slg[nd][t] = v; soff[nd][t] = (uint)s * HSTR; }
    mx = fmaxf(mx, v);
  }
  mx = waveReduceMax(mx);
  if (l == 0) wredm[wv] = mx;
  __syncthreads();
  mx = fmaxf(wredm[nd * 2], wredm[nd * 2 + 1]);
  // ---- sweep 2: exp + per-wave sum ----
  float sum = 0.f;
  if (staged) {
    for (int t = myS + l; t < myE; t += 64) {
      float e = __expf(slg[nd][t] - mx);
      slg[nd][t] = e;
      sum += e;
    }
  } else if (act) {
    for (int t = myS + l; t < myE; t += 64) {
      int s = srcs[s0 + t];
      float v = als[s] + ad;
      v = v >= 0.f ? v : 0.2f * v;
      sum += __expf(v - mx);
    }
  }
  sum = waveReduceSum(sum);
  if (l == 0) wreds[wv] = sum;
  __syncthreads();
  float inv = act ? 1.0f / (wreds[nd * 2] + wreds[nd * 2 + 1]) : 0.f;
  // ---- sweep 3: gather, one masked ILP block per 16 edges ----
  float ax = 0.f, ay = 0.f, az = 0.f, aw = 0.f;
  if (staged) {
    if (D == 128) {
      int g = l >> 5, j = l & 31;
      for (int i = myS; i < myE; i += 16) {
        int c8 = min((myE - i - g + 1) >> 1, 8);  // half-wave-uniform
        float p[8]; uint of[8]; uint2 u[8];
#pragma unroll
        for (int r = 0; r < 8; ++r) if (r < c8) {
          int idx = i + 2 * r + g;
          p[r] = slg[nd][idx];
          of[r] = soff[nd][idx];
        }
#pragma unroll
        for (int r = 0; r < 8; ++r) if (r < c8) u[r] = Hr[(size_t)of[r] + j];
#pragma unroll
        for (int r = 0; r < 8; ++r) if (r < c8) {
          ax += p[r] * h_lo(u[r].x); ay += p[r] * h_hi(u[r].x);
          az += p[r] * h_lo(u[r].y); aw += p[r] * h_hi(u[r].y);
        }
      }
    } else {
      int g = l >> 4, j = l & 15;
      for (int i = myS; i < myE; i += 16) {
        int c4 = min((myE - i - g + 3) >> 2, 4);  // quarter-wave-uniform
        float p[4]; uint of[4]; uint2 u[4];
#pragma unroll
        for (int r = 0; r < 4; ++r) if (r < c4) {
          int idx = i + 4 * r + g;
          p[r] = slg[nd][idx];
          of[r] = soff[nd][idx];
        }
#pragma unroll
        for (int r = 0; r < 4; ++r) if (r < c4) u[r] = Hr[(size_t)of[r] + j];
#pragma unroll
        for (int r = 0; r < 4; ++r) if (r < c4) {
          ax += p[r] * h_lo(u[r].x); ay += p[r] * h_hi(u[r].x);
          az += p[r] * h_lo(u[r].y); aw += p[r] * h_hi(u[r].y);
        }
      }
    }
  } else if (act) {
    // slow generic path (deg > CAP; statistically never for this graph)
    if (D == 128) {
      int g = l >> 5, j = l & 31;
      for (int idx = myS + g; idx < myE; idx += 2) {
        int s = srcs[s0 + idx];
        float v = als[s] + ad;
        v = v >= 0.f ? v : 0.2f * v;
        float p = __expf(v - mx);
        uint2 u = Hr[(size_t)s * HSTR + j];
        ax += p * h_lo(u.x); ay += p * h_hi(u.x);
        az += p * h_lo(u.y); aw += p * h_hi(u.y);
      }
    } else {
      int g = l >> 4, j = l & 15;
      for (int idx = myS + g; idx < myE; idx += 4) {
        int s = srcs[s0 + idx];
        float v = als[s] + ad;
        v = v >= 0.f ? v : 0.2f * v;
        float p = __expf(v - mx);
        uint2 u = Hr[(size_t)s * HSTR + j];
        ax += p * h_lo(u.x); ay += p * h_hi(u.x);
        az += p * h_lo(u.y); aw += p * h_hi(u.y);
      }
    }
  }
  // ---- cross-wave partial combine ----
  if (q == 1) {
    pacc[nd][l][0] = ax; pacc[nd][l][1] = ay;
    pacc[nd][l][2] = az; pacc[nd][l][3] = aw;
  }
  __syncthreads();
  if (q == 1 || !act) return;  // no block-wide syncs below
  ax += pacc[nd][l][0]; ay += pacc[nd][l][1];
  az += pacc[nd][l][2]; aw += pacc[nd][l][3];
  // ---- epilogue (wave 0 of each node) ----
  if (D == 128) {
    ax += __shfl_xor(ax, 32); ay += __shfl_xor(ay, 32);
    az += __shfl_xor(az, 32); aw += __shfl_xor(aw, 32);
    if (l < 32) {
      float4 bv = ((const float4*)bias)[l];
      float v0 = ax * inv + bv.x, v1 = ay * inv + bv.y;
      float v2 = az * inv + bv.z, v3 = aw * inv + bv.w;
      if (MODE == 1) {
        v0 = fmaxf(v0, 0.f); v1 = fmaxf(v1, 0.f);
        v2 = fmaxf(v2, 0.f); v3 = fmaxf(v3, 0.f);
      }
      ((float4*)(out + (size_t)w * 128))[l] = make_float4(v0, v1, v2, v3);
    }
  } else {
    ax += __shfl_xor(ax, 16); ay += __shfl_xor(ay, 16);
    az += __shfl_xor(az, 16); aw += __shfl_xor(aw, 16);
    ax += __shfl_xor(ax, 32); ay += __shfl_xor(ay, 32);
    az += __shfl_xor(az, 32); aw += __shfl_xor(aw, 32);
    int j = l & 15;
    float4 bv = ((const float4*)bias)[j];
    float v0 = ax * inv + bv.x, v1 = ay * inv + bv.y;
    float v2 = az * inv + bv.z, v3 = aw * inv + bv.w;
    if (MODE == 2) {
      float ss = v0 * v0 + v1 * v1 + v2 * v2 + v3 * v3;
      ss += __shfl_xor(ss, 1); ss += __shfl_xor(ss, 2);
      ss += __shfl_xor(ss, 4); ss += __shfl_xor(ss, 8);
      float sc = 1.0f / fmaxf(sqrtf(ss), 1e-12f);
      v0 *= sc; v1 *= sc; v2 *= sc; v3 *= sc;
    }
    if (l < 16) ((float4*)(out + (size_t)w * 64))[j] = make_float4(v0, v1, v2, v3);
    if (MODE == 2) {
      if (l < 16) ((float4*)&sz[nd][0])[j] = make_float4(v0, v1, v2, v3);
      __builtin_amdgcn_wave_barrier();
      int kk = l >> 2, p = l & 3;
      const float* zr = &sz[nd][p * 16];
      const float* cr = &scl[kk][p * 16];
      float s = 0.f;
#pragma unroll
      for (int d = 0; d < 16; ++d) {
        float df = zr[d] - cr[d];
        s += df * df;
      }
      s += __shfl_xor(s, 1);
      s += __shfl_xor(s, 2);
      float qv = 1.0f / (1.0f + s) + 1e-7f;
      float t = qv;
      t += __shfl_xor(t, 4);
      t += __shfl_xor(t, 8);
      t += __shfl_xor(t, 16);
      t += __shfl_xor(t, 32);
      if (p == 0) qout[(size_t)w * 16 + kk] = qv / t;
    }
  }
}

extern "C" void kernel_launch(void* const* d_in, const int* in_sizes, int n_in,
                              void* d_out, int out_size, void* d_ws, size_t ws_size,
                              hipStream_t stream) {
  const float* x = (const float*)d_in[0];
  const int* ei = (const int*)d_in[1];
  const float* W1 = (const float*)d_in[2];
  const float* a1s = (const float*)d_in[3];
  const float* a1d = (const float*)d_in[4];
  const float* b1 = (const float*)d_in[5];
  const float* W2 = (const float*)d_in[6];
  const float* a2s = (const float*)d_in[7];
  const float* a2d = (const float*)d_in[8];
  const float* b2 = (const float*)d_in[9];
  const float* W3 = (const float*)d_in[10];
  const float* a3s = (const float*)d_in[11];
  const float* a3d = (const float*)d_in[12];
  const float* b3 = (const float*)d_in[13];
  const float* W4 = (const float*)d_in[14];
  const float* a4s = (const float*)d_in[15];
  const float* a4d = (const float*)d_in[16];
  const float* b4 = (const float*)d_in[17];
  const float* cluster = (const float*)d_in[18];

  float* out = (float*)d_out;
  float* z = out;                       // [N,64]
  float* xhat = out + (size_t)NN * 64;  // [N,128]
  float* qout = xhat + (size_t)NN * 128;

  const int ET = NE + NN;
  float* wsf = (float*)d_ws;
  float* X = wsf;          wsf += (size_t)NN * 128;  // fp32 activations
  ushort* H = (ushort*)wsf; wsf += (size_t)NN * 64;  // NN*128 fp16
  float* als = wsf;        wsf += NN;
  float* ald = wsf;        wsf += NN;
  int* indptr = (int*)wsf; wsf += NN + 1;
  int* srcs = (int*)wsf;   wsf += ET;
  uint* ebuf = (uint*)wsf; wsf += (size_t)NBK * BCAP;
  int* bcnt = (int*)wsf;   wsf += NBK;
  ushort* wfhi = (ushort*)wsf; wsf += WTOT / 2;
  ushort* wflo = (ushort*)wsf; wsf += WTOT / 2;

  const int* esrc = ei;
  const int* edst = ei + NE;

  const int TB = 256;
  const int gA = (NN + 1) / 2;  // 2 nodes per block (2 waves per node)
  const int gB = (ET + 4095) / 4096;

  // ---- CSR build + W pre-permute ----
  k_wprep<<<(WTOT + 255) / 256, 256, 0, stream>>>(W1, W2, W3, W4, wfhi, wflo, bcnt);
  k_bucket<<<gB, 256, 0, stream>>>(esrc, edst, ebuf, bcnt);
  k_csr<<<NBK, 256, 0, stream>>>(ebuf, bcnt, indptr, srcs);

  // ---- Layer 1 (l2norm fused into A-fragment load) ----
  k_gemm_mfma<128, 128, true><<<GEMM_GRID, 256, 0, stream>>>(
      x, wfhi, wflo, a1s, a1d, H, als, ald, NN);
  k_attn_aggr<128, 1><<<gA, TB, 0, stream>>>(indptr, srcs, als, ald, H, b1, X,
                                             nullptr, nullptr, NN);

  // ---- Layer 2 -> z (l2norm + q fused in epilogue) ----
  k_gemm_mfma<128, 64, false><<<GEMM_GRID, 256, 0, stream>>>(
      X, wfhi + 16384, wflo + 16384, a2s, a2d, H, als, ald, NN);
  k_attn_aggr<64, 2><<<gA, TB, 0, stream>>>(indptr, srcs, als, ald, H, b2, z,
                                            cluster, qout, NN);

  // ---- Layer 3 ----
  k_gemm_mfma<64, 128, false><<<GEMM_GRID, 256, 0, stream>>>(
      z, wfhi + 24576, wflo + 24576, a3s, a3d, H, als, ald, NN);
  k_attn_aggr<128, 1><<<gA, TB, 0, stream>>>(indptr, srcs, als, ald, H, b3, X,
                                             nullptr, nullptr, NN);

  // ---- Layer 4 -> x_hat ----
  k_gemm_mfma<128, 128, false><<<GEMM_GRID, 256, 0, stream>>>(
      X, wfhi + 32768, wflo + 32768, a4s, a4d, H, als, ald, NN);
  k_attn_aggr<128, 0><<<gA, TB, 0, stream>>>(indptr, srcs, als, ald, H, b4, xhat,
                                             nullptr, nullptr, NN);
}

// Round 13
// 244.159 us; speedup vs baseline: 1.4357x; 1.4357x over previous
//
#include <hip/hip_runtime.h>
#include <hip/hip_fp16.h>

#define NN 50000
#define NE 800000
#define NBK 196        // ceil(NN/256) node-range buckets
#define BCAP 8192      // per-bucket edge capacity (mean ~4350)
#define GEMM_GRID 391  // 782 row-tiles, 2 per block
#define WTOT 49152     // W1 16384 + W2 8192 + W3 8192 + W4 16384

typedef unsigned int uint;
typedef unsigned short ushort;
typedef __attribute__((ext_vector_type(8))) short short8v;
typedef __attribute__((ext_vector_type(4))) float float4v;

static __device__ __forceinline__ float waveReduceSum(float v) {
#pragma unroll
  for (int o = 32; o > 0; o >>= 1) v += __shfl_xor(v, o);
  return v;
}
static __device__ __forceinline__ float waveReduceMax(float v) {
#pragma unroll
  for (int o = 32; o > 0; o >>= 1) v = fmaxf(v, __shfl_xor(v, o));
  return v;
}
static __device__ __forceinline__ uint f2bf(float f) {
  uint u = __float_as_uint(f);
  return (u + 0x7fffu + ((u >> 16) & 1u)) >> 16;  // RNE; inputs finite
}
// fp16 pair unpack (H storage)
static __device__ __forceinline__ float h_lo(uint u) {
  __half2 h = *(const __half2*)&u;
  return __half2float(h.x);
}
static __device__ __forceinline__ float h_hi(uint u) {
  __half2 h = *(const __half2*)&u;
  return __half2float(h.y);
}
static __device__ __forceinline__ int waveInclScan(int v, int lane) {
#pragma unroll
  for (int o = 1; o < 64; o <<= 1) {
    int u = __shfl_up(v, o);
    if (lane >= o) v += u;
  }
  return v;
}
// split fp32 -> bf16 hi + bf16 lo (x ~= hi + lo, residual ~2^-16 relative)
static __device__ __forceinline__ void split8(const float* f, short8v& hi, short8v& lo) {
#pragma unroll
  for (int j = 0; j < 8; ++j) {
    uint h = f2bf(f[j]);
    hi[j] = (short)h;
    float hf = __uint_as_float(h << 16);
    lo[j] = (short)f2bf(f[j] - hf);
  }
}

// ---------------- bucketed CSR build ----------------
__global__ __launch_bounds__(256) void k_bucket(
    const int* __restrict__ esrc, const int* __restrict__ edst,
    uint* __restrict__ ebuf, int* __restrict__ bcnt) {
  __shared__ int hist[NBK];
  __shared__ int gbase[NBK];
  int tid = threadIdx.x;
  for (int i = tid; i < NBK; i += 256) hist[i] = 0;
  __syncthreads();
  const int ET = NE + NN;
  int base = blockIdx.x * 4096;
  int myb[16];
  uint mypk[16];
#pragma unroll
  for (int j = 0; j < 16; ++j) {
    int e = base + j * 256 + tid;  // coalesced per j
    int s, d;
    if (e < NE) { s = esrc[e]; d = edst[e]; }
    else if (e < ET) { s = e - NE; d = s; }   // self loop
    else { myb[j] = -1; continue; }
    int b = d >> 8;
    myb[j] = b;
    mypk[j] = (uint)s | ((uint)(d & 255) << 16);
    atomicAdd(&hist[b], 1);
  }
  __syncthreads();
  for (int i = tid; i < NBK; i += 256) {
    int h = hist[i];
    gbase[i] = h > 0 ? atomicAdd(&bcnt[i], h) : 0;
    hist[i] = 0;  // reuse as cursor
  }
  __syncthreads();
#pragma unroll
  for (int j = 0; j < 16; ++j) {
    int b = myb[j];
    if (b < 0) continue;
    int r = atomicAdd(&hist[b], 1);
    int pos = gbase[b] + r;
    if (pos < BCAP) ebuf[(size_t)b * BCAP + pos] = mypk[j];
  }
}
__global__ __launch_bounds__(256) void k_csr(
    const uint* __restrict__ ebuf, const int* __restrict__ bcnt,
    int* __restrict__ indptr, int* __restrict__ srcs) {
  __shared__ int h[256];
  __shared__ int cur[256];
  __shared__ int wsm[4];
  __shared__ int bbs;
  int tid = threadIdx.x, b = blockIdx.x;
  int lane = tid & 63, wv = tid >> 6;
  int v = (tid < NBK) ? bcnt[tid] : 0;
  int inc = waveInclScan(v, lane);
  if (lane == 63) wsm[wv] = inc;
  __syncthreads();
  int woff = 0;
  for (int k = 0; k < wv; ++k) woff += wsm[k];
  if (tid == b) bbs = inc - v + woff;
  h[tid] = 0;
  __syncthreads();
  int bbase = bbs;
  int cnt = bcnt[b];
  const uint* eb = ebuf + (size_t)b * BCAP;
  for (int i = tid; i < cnt; i += 256) atomicAdd(&h[eb[i] >> 16], 1);
  __syncthreads();
  int hv = h[tid];
  int inc2 = waveInclScan(hv, lane);
  if (lane == 63) wsm[wv] = inc2;
  __syncthreads();
  int woff2 = 0;
  for (int k = 0; k < wv; ++k) woff2 += wsm[k];
  int nodeExcl = inc2 - hv + woff2;
  int node = b * 256 + tid;
  if (node < NN) indptr[node] = bbase + nodeExcl;
  if (node == NN - 1) indptr[NN] = bbase + nodeExcl + hv;
  cur[tid] = nodeExcl;
  __syncthreads();
  for (int i = tid; i < cnt; i += 256) {
    uint pk = eb[i];
    int r = atomicAdd(&cur[pk >> 16], 1);
    srcs[bbase + r] = (int)(pk & 0xffffu);
  }
}

// ---------------- W pre-permute (+ bcnt zero) ----------------
__global__ void k_wprep(const float* __restrict__ W1, const float* __restrict__ W2,
                        const float* __restrict__ W3, const float* __restrict__ W4,
                        ushort* __restrict__ hi, ushort* __restrict__ lo,
                        int* __restrict__ bcnt) {
  int i = blockIdx.x * 256 + threadIdx.x;
  if (i < NBK) bcnt[i] = 0;  // block 0 zeroes bucket counters
  if (i >= WTOT) return;
  const float* W; int DO, base;
  if (i < 16384)      { W = W1; DO = 128; base = 0; }
  else if (i < 24576) { W = W2; DO = 64;  base = 16384; }
  else if (i < 32768) { W = W3; DO = 128; base = 24576; }
  else                { W = W4; DO = 128; base = 32768; }
  int idx = i - base;
  int k = idx / DO, col = idx % DO;
  float w = W[idx];
  uint h = f2bf(w);
  float hf = __uint_as_float(h << 16);
  uint l2 = f2bf(w - hf);
  int CT = DO >> 4;
  int fo = base + (((k >> 5) * CT + (col >> 4)) * 64 + ((col & 15) | (((k >> 3) & 3) << 4))) * 8 + (k & 7);
  hi[fo] = (ushort)h;
  lo[fo] = (ushort)l2;
}

// ---------------- MFMA GEMM (split-bf16, fp32-grade) + logit dots ----------
// H stored as packed fp16 pairs. W pre-permuted (k_wprep): linear uint4 stage.
// mfma_f32_16x16x32_bf16 layouts (guide §3 / m89):
//   A[l&15][8*(l>>4)+e], B[8*(l>>4)+e][l&15], D[4*(l>>4)+j][l&15]
template <int K, int DO, bool NORM>
__global__ __launch_bounds__(256) void k_gemm_mfma(
    const float* __restrict__ X, const ushort* __restrict__ Whi,
    const ushort* __restrict__ Wlo,
    const float* __restrict__ avs, const float* __restrict__ avd,
    ushort* __restrict__ H, float* __restrict__ als, float* __restrict__ ald, int n) {
  constexpr int KS = K / 32, CT = DO / 16;
  constexpr int W4N = K * DO / 8;  // uint4 words per array
  __shared__ ushort sWhi[K * DO];
  __shared__ ushort sWlo[K * DO];
  __shared__ float sas[DO], sad[DO];
  int tid = threadIdx.x;
  for (int i = tid; i < DO; i += 256) { sas[i] = avs[i]; sad[i] = avd[i]; }
  {
    const uint4* ghi = (const uint4*)Whi;
    const uint4* glo = (const uint4*)Wlo;
    uint4* shi = (uint4*)sWhi;
    uint4* slo = (uint4*)sWlo;
    for (int i = tid; i < W4N; i += 256) { shi[i] = ghi[i]; slo[i] = glo[i]; }
  }
  __syncthreads();
  int lane = tid & 63, wv = tid >> 6;
  int ntiles = (n + 63) >> 6;
  for (int tile = blockIdx.x; tile < ntiles; tile += gridDim.x) {
    int r0 = tile * 64 + wv * 16;
    if (r0 >= n) continue;
    int row = r0 + (lane & 15);
    int sub = lane >> 4;
    const float* xrow = X + (size_t)row * K;
    float xr[KS][8];
#pragma unroll
    for (int s = 0; s < KS; ++s) {
      *(float4*)&xr[s][0] = *(const float4*)(xrow + s * 32 + sub * 8);
      *(float4*)&xr[s][4] = *(const float4*)(xrow + s * 32 + sub * 8 + 4);
    }
    if (NORM) {
      float ss = 0.f;
#pragma unroll
      for (int s = 0; s < KS; ++s)
#pragma unroll
        for (int j = 0; j < 8; ++j) ss += xr[s][j] * xr[s][j];
      ss += __shfl_xor(ss, 16);
      ss += __shfl_xor(ss, 32);
      float sc = 1.0f / fmaxf(sqrtf(ss), 1e-12f);
#pragma unroll
      for (int s = 0; s < KS; ++s)
#pragma unroll
        for (int j = 0; j < 8; ++j) xr[s][j] *= sc;
    }
    float4v acc[CT];
#pragma unroll
    for (int c = 0; c < CT; ++c) acc[c] = (float4v){0.f, 0.f, 0.f, 0.f};
#pragma unroll
    for (int s = 0; s < KS; ++s) {
      short8v ahi, alo;
      split8(xr[s], ahi, alo);
#pragma unroll
      for (int c = 0; c < CT; ++c) {
        short8v bhi = *(const short8v*)&sWhi[(s * CT + c) * 512 + lane * 8];
        short8v blo = *(const short8v*)&sWlo[(s * CT + c) * 512 + lane * 8];
        acc[c] = __builtin_amdgcn_mfma_f32_16x16x32_bf16(ahi, bhi, acc[c], 0, 0, 0);
        acc[c] = __builtin_amdgcn_mfma_f32_16x16x32_bf16(ahi, blo, acc[c], 0, 0, 0);
        acc[c] = __builtin_amdgcn_mfma_f32_16x16x32_bf16(alo, bhi, acc[c], 0, 0, 0);
      }
    }
    int rbase = r0 + (sub << 2);
    float alsp[4] = {0.f, 0.f, 0.f, 0.f};
    float aldp[4] = {0.f, 0.f, 0.f, 0.f};
#pragma unroll
    for (int c = 0; c < CT; ++c) {
      int col = (c << 4) + (lane & 15);
      float as_ = sas[col], ad_ = sad[col];
#pragma unroll
      for (int j = 0; j < 4; ++j) {
        float v = acc[c][j];
        alsp[j] += v * as_;
        aldp[j] += v * ad_;
        uint bv = (uint)__half_as_ushort(__float2half(v));
        uint nb = __shfl_xor(bv, 1);
        if (!(lane & 1)) {
          *(uint*)&H[(size_t)(rbase + j) * DO + col] = bv | (nb << 16);
        }
      }
    }
#pragma unroll
    for (int j = 0; j < 4; ++j) {
      float vs = alsp[j], vd = aldp[j];
#pragma unroll
      for (int o = 1; o < 16; o <<= 1) { vs += __shfl_xor(vs, o); vd += __shfl_xor(vd, o); }
      if ((lane & 15) == 0) { als[rbase + j] = vs; ald[rbase + j] = vd; }
    }
  }
}

// ---------------- fused per-node softmax + aggregation (one wave/node) -----
// Round-11 structure (best known). Sweep 1 now stages precomputed H row
// offsets (src*HSTR) instead of indices -> no 64-bit mul in the gather loop.
// MODE 0: +bias ; MODE 1: +bias,relu ; MODE 2 (D=64): +bias, l2norm, fused q
template <int D, int MODE>
__global__ __launch_bounds__(256) void k_attn_aggr(
    const int* __restrict__ indptr, const int* __restrict__ srcs,
    const float* __restrict__ als, const float* __restrict__ ald,
    const ushort* __restrict__ H, const float* __restrict__ bias,
    float* __restrict__ out, const float* __restrict__ cluster,
    float* __restrict__ qout, int n) {
  constexpr int CAP = 256;
  constexpr uint HSTR = D / 4;  // uint2 per H row
  __shared__ float slg[4][CAP];
  __shared__ uint soff[4][CAP];
  // +4 pad: kk*68 mod 32 = 4*kk -> 2-way alias (free), vs 16-way at stride 64
  __shared__ float scl[MODE == 2 ? 16 : 1][MODE == 2 ? 68 : 1];
  __shared__ float sz[4][MODE == 2 ? 64 : 4];
  int w = (blockIdx.x * blockDim.x + threadIdx.x) >> 6;
  int l = threadIdx.x & 63;
  int wv = threadIdx.x >> 6;
  if (MODE == 2) {
    for (int i = threadIdx.x; i < 1024; i += 256) scl[i >> 6][i & 63] = cluster[i];
    __syncthreads();
  }
  if (w >= n) return;
  int s0 = indptr[w], s1 = indptr[w + 1];
  int deg = s1 - s0;
  float ad = ald[w];
  float inv;
  float ax = 0.f, ay = 0.f, az = 0.f, aw = 0.f;  // 4 cols per lane
  const uint2* Hr = (const uint2*)H;
  if (deg <= CAP) {
    // sweep 1: gather logits + row offsets into LDS, running max
    float mx = -1e30f;
    for (int t = l; t < deg; t += 64) {
      int s = srcs[s0 + t];
      float v = als[s] + ad;
      v = v >= 0.f ? v : 0.2f * v;
      soff[wv][t] = (uint)s * HSTR;
      slg[wv][t] = v;
      mx = fmaxf(mx, v);
    }
    mx = waveReduceMax(mx);
    // sweep 2: exp in place, sum
    float sum = 0.f;
    for (int t = l; t < deg; t += 64) {
      float e = __expf(slg[wv][t] - mx);
      slg[wv][t] = e;
      sum += e;
    }
    sum = waveReduceSum(sum);
    inv = 1.0f / sum;
    // sweep 3: gather-MLP aggregation
    if (D == 128) {
      int g = l >> 5, j = l & 31;
      int i = 0;
      for (; i + 16 <= deg; i += 16) {  // 8 edges per half-wave in flight
        float p[8]; uint of[8]; uint2 u[8];
#pragma unroll
        for (int r = 0; r < 8; ++r) { int idx = i + 2 * r + g; p[r] = slg[wv][idx]; of[r] = soff[wv][idx]; }
#pragma unroll
        for (int r = 0; r < 8; ++r) u[r] = Hr[(size_t)of[r] + j];
#pragma unroll
        for (int r = 0; r < 8; ++r) {
          ax += p[r] * h_lo(u[r].x); ay += p[r] * h_hi(u[r].x);
          az += p[r] * h_lo(u[r].y); aw += p[r] * h_hi(u[r].y);
        }
      }
      for (; i + 8 <= deg; i += 8) {
        float p[4]; uint of[4]; uint2 u[4];
#pragma unroll
        for (int r = 0; r < 4; ++r) { int idx = i + 2 * r + g; p[r] = slg[wv][idx]; of[r] = soff[wv][idx]; }
#pragma unroll
        for (int r = 0; r < 4; ++r) u[r] = Hr[(size_t)of[r] + j];
#pragma unroll
        for (int r = 0; r < 4; ++r) {
          ax += p[r] * h_lo(u[r].x); ay += p[r] * h_hi(u[r].x);
          az += p[r] * h_lo(u[r].y); aw += p[r] * h_hi(u[r].y);
        }
      }
      for (; i < deg; i += 2) {
        int idx = i + g;
        if (idx < deg) {
          float p = slg[wv][idx];
          uint2 u = Hr[(size_t)soff[wv][idx] + j];
          ax += p * h_lo(u.x); ay += p * h_hi(u.x);
          az += p * h_lo(u.y); aw += p * h_hi(u.y);
        }
      }
    } else {  // D == 64: quarter-waves
      int g = l >> 4, j = l & 15;
      int i = 0;
      for (; i + 32 <= deg; i += 32) {  // 8 edges per quarter-wave in flight
        float p[8]; uint of[8]; uint2 u[8];
#pragma unroll
        for (int r = 0; r < 8; ++r) { int idx = i + 4 * r + g; p[r] = slg[wv][idx]; of[r] = soff[wv][idx]; }
#pragma unroll
        for (int r = 0; r < 8; ++r) u[r] = Hr[(size_t)of[r] + j];
#pragma unroll
        for (int r = 0; r < 8; ++r) {
          ax += p[r] * h_lo(u[r].x); ay += p[r] * h_hi(u[r].x);
          az += p[r] * h_lo(u[r].y); aw += p[r] * h_hi(u[r].y);
        }
      }
      for (; i + 16 <= deg; i += 16) {
        float p[4]; uint of[4]; uint2 u[4];
#pragma unroll
        for (int r = 0; r < 4; ++r) { int idx = i + 4 * r + g; p[r] = slg[wv][idx]; of[r] = soff[wv][idx]; }
#pragma unroll
        for (int r = 0; r < 4; ++r) u[r] = Hr[(size_t)of[r] + j];
#pragma unroll
        for (int r = 0; r < 4; ++r) {
          ax += p[r] * h_lo(u[r].x); ay += p[r] * h_hi(u[r].x);
          az += p[r] * h_lo(u[r].y); aw += p[r] * h_hi(u[r].y);
        }
      }
      for (; i < deg; i += 4) {
        int idx = i + g;
        if (idx < deg) {
          float p = slg[wv][idx];
          uint2 u = Hr[(size_t)soff[wv][idx] + j];
          ax += p * h_lo(u.x); ay += p * h_hi(u.x);
          az += p * h_lo(u.y); aw += p * h_hi(u.y);
        }
      }
    }
  } else {
    // fallback: deg > CAP (kept for correctness)
    float mx = -1e30f;
    for (int t = l; t < deg; t += 64) {
      int s = srcs[s0 + t];
      float v = als[s] + ad;
      v = v >= 0.f ? v : 0.2f * v;
      mx = fmaxf(mx, v);
    }
    mx = waveReduceMax(mx);
    float sum = 0.f;
    for (int t = l; t < deg; t += 64) {
      int s = srcs[s0 + t];
      float v = als[s] + ad;
      v = v >= 0.f ? v : 0.2f * v;
      sum += __expf(v - mx);
    }
    sum = waveReduceSum(sum);
    inv = 1.0f / sum;
    for (int base = 0; base < deg; base += 64) {
      int t = base + l;
      if (t < deg) {
        int s = srcs[s0 + t];
        float v = als[s] + ad;
        v = v >= 0.f ? v : 0.2f * v;
        soff[wv][l] = (uint)s * HSTR;
        slg[wv][l] = __expf(v - mx);
      }
      __builtin_amdgcn_wave_barrier();
      int m = min(64, deg - base);
      if (D == 128) {
        int g = l >> 5, j = l & 31;
        for (int i2 = g; i2 < m; i2 += 2) {
          float p = slg[wv][i2];
          uint2 u = Hr[(size_t)soff[wv][i2] + j];
          ax += p * h_lo(u.x); ay += p * h_hi(u.x);
          az += p * h_lo(u.y); aw += p * h_hi(u.y);
        }
      } else {
        int g = l >> 4, j = l & 15;
        for (int i2 = g; i2 < m; i2 += 4) {
          float p = slg[wv][i2];
          uint2 u = Hr[(size_t)soff[wv][i2] + j];
          ax += p * h_lo(u.x); ay += p * h_hi(u.x);
          az += p * h_lo(u.y); aw += p * h_hi(u.y);
        }
      }
      __builtin_amdgcn_wave_barrier();
    }
  }
  // combine edge-parity groups + epilogue (lane owns 4 cols: 4j..4j+3)
  if (D == 128) {
    ax += __shfl_xor(ax, 32); ay += __shfl_xor(ay, 32);
    az += __shfl_xor(az, 32); aw += __shfl_xor(aw, 32);
    if (l < 32) {
      float4 bv = ((const float4*)bias)[l];
      float v0 = ax * inv + bv.x, v1 = ay * inv + bv.y;
      float v2 = az * inv + bv.z, v3 = aw * inv + bv.w;
      if (MODE == 1) {
        v0 = fmaxf(v0, 0.f); v1 = fmaxf(v1, 0.f);
        v2 = fmaxf(v2, 0.f); v3 = fmaxf(v3, 0.f);
      }
      ((float4*)(out + (size_t)w * 128))[l] = make_float4(v0, v1, v2, v3);
    }
  } else {
    ax += __shfl_xor(ax, 16); ay += __shfl_xor(ay, 16);
    az += __shfl_xor(az, 16); aw += __shfl_xor(aw, 16);
    ax += __shfl_xor(ax, 32); ay += __shfl_xor(ay, 32);
    az += __shfl_xor(az, 32); aw += __shfl_xor(aw, 32);
    int j = l & 15;
    float4 bv = ((const float4*)bias)[j];
    float v0 = ax * inv + bv.x, v1 = ay * inv + bv.y;
    float v2 = az * inv + bv.z, v3 = aw * inv + bv.w;
    if (MODE == 2) {
      float ss = v0 * v0 + v1 * v1 + v2 * v2 + v3 * v3;
      ss += __shfl_xor(ss, 1); ss += __shfl_xor(ss, 2);
      ss += __shfl_xor(ss, 4); ss += __shfl_xor(ss, 8);
      float sc = 1.0f / fmaxf(sqrtf(ss), 1e-12f);
      v0 *= sc; v1 *= sc; v2 *= sc; v3 *= sc;
    }
    if (l < 16) ((float4*)(out + (size_t)w * 64))[j] = make_float4(v0, v1, v2, v3);
    if (MODE == 2) {
      // fused q: z row -> LDS, per-lane cluster-distance partials
      if (l < 16) ((float4*)&sz[wv][0])[j] = make_float4(v0, v1, v2, v3);
      __builtin_amdgcn_wave_barrier();
      int kk = l >> 2, p = l & 3;
      const float* zr = &sz[wv][p * 16];
      const float* cr = &scl[kk][p * 16];
      float s = 0.f;
#pragma unroll
      for (int d = 0; d < 16; ++d) {
        float df = zr[d] - cr[d];
        s += df * df;
      }
      s += __shfl_xor(s, 1);
      s += __shfl_xor(s, 2);
      float qv = 1.0f / (1.0f + s) + 1e-7f;
      float t = qv;
      t += __shfl_xor(t, 4);
      t += __shfl_xor(t, 8);
      t += __shfl_xor(t, 16);
      t += __shfl_xor(t, 32);
      if (p == 0) qout[(size_t)w * 16 + kk] = qv / t;
    }
  }
}

extern "C" void kernel_launch(void* const* d_in, const int* in_sizes, int n_in,
                              void* d_out, int out_size, void* d_ws, size_t ws_size,
                              hipStream_t stream) {
  const float* x = (const float*)d_in[0];
  const int* ei = (const int*)d_in[1];
  const float* W1 = (const float*)d_in[2];
  const float* a1s = (const float*)d_in[3];
  const float* a1d = (const float*)d_in[4];
  const float* b1 = (const float*)d_in[5];
  const float* W2 = (const float*)d_in[6];
  const float* a2s = (const float*)d_in[7];
  const float* a2d = (const float*)d_in[8];
  const float* b2 = (const float*)d_in[9];
  const float* W3 = (const float*)d_in[10];
  const float* a3s = (const float*)d_in[11];
  const float* a3d = (const float*)d_in[12];
  const float* b3 = (const float*)d_in[13];
  const float* W4 = (const float*)d_in[14];
  const float* a4s = (const float*)d_in[15];
  const float* a4d = (const float*)d_in[16];
  const float* b4 = (const float*)d_in[17];
  const float* cluster = (const float*)d_in[18];

  float* out = (float*)d_out;
  float* z = out;                       // [N,64]
  float* xhat = out + (size_t)NN * 64;  // [N,128]
  float* qout = xhat + (size_t)NN * 128;

  const int ET = NE + NN;
  float* wsf = (float*)d_ws;
  float* X = wsf;          wsf += (size_t)NN * 128;  // fp32 activations
  ushort* H = (ushort*)wsf; wsf += (size_t)NN * 64;  // NN*128 fp16
  float* als = wsf;        wsf += NN;
  float* ald = wsf;        wsf += NN;
  int* indptr = (int*)wsf; wsf += NN + 1;
  int* srcs = (int*)wsf;   wsf += ET;
  uint* ebuf = (uint*)wsf; wsf += (size_t)NBK * BCAP;
  int* bcnt = (int*)wsf;   wsf += NBK;
  ushort* wfhi = (ushort*)wsf; wsf += WTOT / 2;
  ushort* wflo = (ushort*)wsf; wsf += WTOT / 2;

  const int* esrc = ei;
  const int* edst = ei + NE;

  const int TB = 256;
  const int gW = (NN + 3) / 4;  // one wave per node
  const int gB = (ET + 4095) / 4096;

  // ---- CSR build + W pre-permute ----
  k_wprep<<<(WTOT + 255) / 256, 256, 0, stream>>>(W1, W2, W3, W4, wfhi, wflo, bcnt);
  k_bucket<<<gB, 256, 0, stream>>>(esrc, edst, ebuf, bcnt);
  k_csr<<<NBK, 256, 0, stream>>>(ebuf, bcnt, indptr, srcs);

  // ---- Layer 1 (l2norm fused into A-fragment load) ----
  k_gemm_mfma<128, 128, true><<<GEMM_GRID, 256, 0, stream>>>(
      x, wfhi, wflo, a1s, a1d, H, als, ald, NN);
  k_attn_aggr<128, 1><<<gW, TB, 0, stream>>>(indptr, srcs, als, ald, H, b1, X,
                                             nullptr, nullptr, NN);

  // ---- Layer 2 -> z (l2norm + q fused in epilogue) ----
  k_gemm_mfma<128, 64, false><<<GEMM_GRID, 256, 0, stream>>>(
      X, wfhi + 16384, wflo + 16384, a2s, a2d, H, als, ald, NN);
  k_attn_aggr<64, 2><<<gW, TB, 0, stream>>>(indptr, srcs, als, ald, H, b2, z,
                                            cluster, qout, NN);

  // ---- Layer 3 ----
  k_gemm_mfma<64, 128, false><<<GEMM_GRID, 256, 0, stream>>>(
      z, wfhi + 24576, wflo + 24576, a3s, a3d, H, als, ald, NN);
  k_attn_aggr<128, 1><<<gW, TB, 0, stream>>>(indptr, srcs, als, ald, H, b3, X,
                                             nullptr, nullptr, NN);

  // ---- Layer 4 -> x_hat ----
  k_gemm_mfma<128, 128, false><<<GEMM_GRID, 256, 0, stream>>>(
      X, wfhi + 32768, wflo + 32768, a4s, a4d, H, als, ald, NN);
  k_attn_aggr<128, 0><<<gW, TB, 0, stream>>>(indptr, srcs, als, ald, H, b4, xhat,
                                             nullptr, nullptr, NN);
}